// Round 5
// baseline (275.241 us; speedup 1.0000x reference)
//
#include <hip/hip_runtime.h>
#include <hip/hip_fp16.h>
#include <stdint.h>

// Attention: qkv [8, 1536, 2048] f32, H=8, ch=64, L=2048.
// V6: two-kernel plan.
//  Kernel 1 (prep): streaming f32->f16 convert of qkv into d_ws (48 MB):
//    Qt [64bh][2048 t][64 c]  (scale 0.125*log2e folded)   @ half offset 0
//    Kt [64bh][2048 s][64 c]  (transposed)                 @ 8388608
//    Vn [64bh][64 c][2048 s]  (natural)                    @ 16777216
//    5120 blocks, full-MLP streaming -> cold HBM read happens ONCE at ~6 TB/s
//    instead of demand-paced inside the attention loop (the ~100us cold gap).
//  Kernel 2 (attn): V1's proven math, but staging is 4x global_load_lds(16B)
//    per thread (pre-swizzled GLOBAL source + linear LDS dest + swizzled
//    reads), double-buffered K/V (f16, 32 KB) + Pt[128][32] (8 KB) = 40 KB
//    -> 4 blocks/CU. Zero staging VGPRs, zero cvt VALU, one vmcnt(0)+barrier
//    per tile. No setprio (V5 showed it regresses this lockstep structure).
//  Fallback: ws too small -> verbatim V1 kernel.
//
// LDS swizzles (16B granules):
//   Kt (s,c): phys_g = g ^ (((s>>2)^s)&7)
//   Vt (c,s): phys_g = g ^ (c&7)
//   Pt (t,s') 64B rows: phys_g = g ^ ((row>>1)&3)

typedef _Float16 half8 __attribute__((ext_vector_type(8)));
typedef _Float16 half4 __attribute__((ext_vector_type(4)));
typedef float floatx4 __attribute__((ext_vector_type(4)));

// ---------------------------------------------------------------- prep pass
__global__ __launch_bounds__(256) void prep_kernel(const float* __restrict__ qkv,
                                                   _Float16* __restrict__ ws)
{
    const int tid = threadIdx.x;
    const int blk = blockIdx.x;
    const float C = 0.125f * 1.44269504088896f;

    if (blk < 4096) {
        // transpose+convert Q (mat 0, scaled by C) / K (mat 1): 64x64 tile
        __shared__ _Float16 Tt[64 * 64];
        const int mat  = blk >> 11;
        const int bh   = (blk >> 5) & 63;
        const int tile = blk & 31;
        const float scale = (mat == 0) ? C : 1.0f;
        const float* src = qkv + (size_t)bh * 393216 + (size_t)mat * 131072 + tile * 64;
        _Float16* dst = ws + (size_t)mat * 8388608 + (size_t)bh * 131072 + tile * 4096;

        const int c4 = (tid >> 4) * 4;
        const int x4 = (tid & 15) * 4;
        floatx4 v[4];
        #pragma unroll
        for (int r = 0; r < 4; ++r)
            v[r] = *reinterpret_cast<const floatx4*>(src + (c4 + r) * 2048 + x4);
        #pragma unroll
        for (int j = 0; j < 4; ++j) {
            const int x  = x4 + j;
            const int sw = ((x >> 2) ^ x) & 7;
            half4 h = { (_Float16)(v[0][j] * scale), (_Float16)(v[1][j] * scale),
                        (_Float16)(v[2][j] * scale), (_Float16)(v[3][j] * scale) };
            *reinterpret_cast<half4*>(&Tt[x * 64 + ((((c4 >> 3) ^ sw) & 7) << 3) + (c4 & 7)]) = h;
        }
        __syncthreads();
        #pragma unroll
        for (int i = 0; i < 2; ++i) {
            const int slot = tid + 256 * i;
            const int x  = slot >> 3;
            const int g  = slot & 7;
            const int sw = ((x >> 2) ^ x) & 7;
            half8 hv = *reinterpret_cast<const half8*>(&Tt[x * 64 + ((g ^ sw) << 3)]);
            *reinterpret_cast<half8*>(dst + x * 64 + g * 8) = hv;
        }
    } else {
        // straight-convert V: 64c x 128s chunk
        const int idx = blk - 4096;
        const int bh  = idx >> 4;
        const int bt  = idx & 15;
        const float* src = qkv + (size_t)bh * 393216 + 262144 + bt * 128;
        _Float16* dst = ws + 16777216 + (size_t)bh * 131072 + bt * 128;
        #pragma unroll
        for (int i = 0; i < 4; ++i) {
            const int h8 = tid + 256 * i;       // 0..1023
            const int c  = h8 >> 4;
            const int s8 = (h8 & 15) * 8;
            floatx4 a = *reinterpret_cast<const floatx4*>(src + c * 2048 + s8);
            floatx4 b = *reinterpret_cast<const floatx4*>(src + c * 2048 + s8 + 4);
            half8 hv = { (_Float16)a[0], (_Float16)a[1], (_Float16)a[2], (_Float16)a[3],
                         (_Float16)b[0], (_Float16)b[1], (_Float16)b[2], (_Float16)b[3] };
            *reinterpret_cast<half8*>(dst + c * 2048 + s8) = hv;
        }
    }
}

// ---------------------------------------------------------------- attn (f16)
__global__ __launch_bounds__(256, 4) void attn_kernel(const _Float16* __restrict__ ws,
                                                      float* __restrict__ out)
{
    __shared__ _Float16 K0[64 * 64], V0[64 * 64];
    __shared__ _Float16 K1[64 * 64], V1[64 * 64];
    __shared__ _Float16 Pt[128 * 32];

    const int tid  = threadIdx.x;
    const int wave = tid >> 6;
    const int lane = tid & 63;
    const int llo  = lane & 15;
    const int lhi  = lane >> 4;

    const int blk  = blockIdx.x;
    const int slot = blk >> 3;
    const int bh   = (blk & 7) * 8 + (slot >> 4);
    const int tile = slot & 15;
    const int t0   = tile * 128;

    const _Float16* qtg = ws + (size_t)bh * 131072;
    const _Float16* ktg = ws + 8388608 + (size_t)bh * 131072;
    const _Float16* vng = ws + 16777216 + (size_t)bh * 131072;

    const float B2 = 6.0f;   // exp2-domain bias

    // ---- Q fragments: direct half8 loads (scale pre-applied in prep)
    half8 qf[2][2];
    const int twbase = t0 + wave * 32;
    #pragma unroll
    for (int nt = 0; nt < 2; ++nt)
        #pragma unroll
        for (int ck = 0; ck < 2; ++ck)
            qf[nt][ck] = *reinterpret_cast<const half8*>(
                qtg + (size_t)(twbase + nt * 16 + llo) * 64 + ck * 32 + lhi * 8);

    // ---- staging slots: slot = tid + 256*i covers 64 rows x 8 granules
    // LDS dest is LINEAR (wave-uniform base + lane*16); swizzle goes on the
    // GLOBAL source granule (inverse == same XOR), reads keep V1's swizzle.
    int krow[2], kgs[2], vgs[2];
    #pragma unroll
    for (int i = 0; i < 2; ++i) {
        const int sl = tid + 256 * i;
        const int row = sl >> 3;
        const int g   = sl & 7;
        krow[i] = row;
        kgs[i]  = ((g ^ (((row >> 2) ^ row) & 7)) & 7) << 3;
        vgs[i]  = ((g ^ (row & 7)) & 7) << 3;
    }

    auto stage = [&](_Float16* Kb, _Float16* Vb, int s0) {
        #pragma unroll
        for (int i = 0; i < 2; ++i)
            __builtin_amdgcn_global_load_lds(
                (const __attribute__((address_space(1))) uint32_t*)
                    (ktg + (size_t)(s0 + krow[i]) * 64 + kgs[i]),
                (__attribute__((address_space(3))) uint32_t*)
                    (Kb + wave * 512 + i * 2048), 16, 0, 0);
        #pragma unroll
        for (int i = 0; i < 2; ++i)
            __builtin_amdgcn_global_load_lds(
                (const __attribute__((address_space(1))) uint32_t*)
                    (vng + (size_t)krow[i] * 2048 + s0 + vgs[i]),
                (__attribute__((address_space(3))) uint32_t*)
                    (Vb + wave * 512 + i * 2048), 16, 0, 0);
    };

    // ---- fragment read offsets (V1 K/V formulas; V3 Pt-32 formulas)
    int kroff[4][2];
    #pragma unroll
    for (int ms = 0; ms < 4; ++ms) {
        const int s  = ms * 16 + llo;
        const int sw = ((s >> 2) ^ s) & 7;
        kroff[ms][0] = s * 64 + (((lhi ^ sw) & 7) << 3);
        kroff[ms][1] = s * 64 + ((((lhi + 4) ^ sw) & 7) << 3);
    }
    int vroff[4][2];
    #pragma unroll
    for (int mc = 0; mc < 4; ++mc) {
        const int row = mc * 16 + llo;
        #pragma unroll
        for (int sk = 0; sk < 2; ++sk)
            vroff[mc][sk] = row * 64 + ((((sk * 4 + lhi) ^ (llo & 7)) & 7) << 3);
    }
    int pwoff[2][2];
    #pragma unroll
    for (int nt = 0; nt < 2; ++nt) {
        const int row = wave * 32 + nt * 16 + llo;
        const int swz = (llo >> 1) & 3;
        #pragma unroll
        for (int ms2 = 0; ms2 < 2; ++ms2)
            pwoff[nt][ms2] = row * 32 + ((((2 * ms2 + (lhi >> 1)) ^ swz) & 3) << 3)
                           + 4 * (lhi & 1);
    }
    int proff[2];
    #pragma unroll
    for (int nt = 0; nt < 2; ++nt) {
        const int row = wave * 32 + nt * 16 + llo;
        proff[nt] = row * 32 + (((lhi ^ ((llo >> 1) & 3)) & 3) << 3);
    }

    floatx4 O[2][4];
    #pragma unroll
    for (int nt = 0; nt < 2; ++nt)
        #pragma unroll
        for (int mc = 0; mc < 4; ++mc)
            O[nt][mc] = (floatx4){0.f, 0.f, 0.f, 0.f};
    float l_run[2] = {0.f, 0.f};

    auto compute = [&](const _Float16* K, const _Float16* V) {
        #pragma unroll
        for (int ph = 0; ph < 2; ++ph) {
            #pragma unroll
            for (int ms2 = 0; ms2 < 2; ++ms2) {
                const int ms = ph * 2 + ms2;
                half8 a0 = *reinterpret_cast<const half8*>(&K[kroff[ms][0]]);
                half8 a1 = *reinterpret_cast<const half8*>(&K[kroff[ms][1]]);
                #pragma unroll
                for (int nt = 0; nt < 2; ++nt) {
                    floatx4 acc = (floatx4){-B2, -B2, -B2, -B2};
                    acc = __builtin_amdgcn_mfma_f32_16x16x32_f16(a0, qf[nt][0], acc, 0, 0, 0);
                    acc = __builtin_amdgcn_mfma_f32_16x16x32_f16(a1, qf[nt][1], acc, 0, 0, 0);
                    half4 phv;
                    float l = 0.f;
                    #pragma unroll
                    for (int r = 0; r < 4; ++r) {
                        const float p = __builtin_amdgcn_exp2f(acc[r]);
                        l += p;
                        phv[r] = (_Float16)p;
                    }
                    l_run[nt] += l;
                    *reinterpret_cast<half4*>(&Pt[pwoff[nt][ms2]]) = phv;
                }
            }
            half8 bp0 = *reinterpret_cast<const half8*>(&Pt[proff[0]]);
            half8 bp1 = *reinterpret_cast<const half8*>(&Pt[proff[1]]);
            #pragma unroll
            for (int mc = 0; mc < 4; ++mc) {
                half8 av = *reinterpret_cast<const half8*>(&V[vroff[mc][ph]]);
                O[0][mc] = __builtin_amdgcn_mfma_f32_16x16x32_f16(av, bp0, O[0][mc], 0, 0, 0);
                O[1][mc] = __builtin_amdgcn_mfma_f32_16x16x32_f16(av, bp1, O[1][mc], 0, 0, 0);
            }
        }
    };

    // ---- prologue: DMA tile 0 into buf0
    stage(K0, V0, 0);
    asm volatile("s_waitcnt vmcnt(0)" ::: "memory");
    __builtin_amdgcn_s_barrier();

    // ---- main loop: stage next tile (DMA, in flight across compute),
    // one vmcnt(0)+barrier per tile.
    #pragma unroll 1
    for (int it = 0; it < 32; it += 2) {
        stage(K1, V1, (it + 1) * 64);
        compute(K0, V0);
        asm volatile("s_waitcnt vmcnt(0)" ::: "memory");
        __builtin_amdgcn_s_barrier();

        if (it + 2 < 32) stage(K0, V0, (it + 2) * 64);
        compute(K1, V1);
        asm volatile("s_waitcnt vmcnt(0)" ::: "memory");
        __builtin_amdgcn_s_barrier();
    }

    // ---- epilogue: reduce l across lhi groups, O/l, store
    float* ob = out + (size_t)bh * 131072;
    #pragma unroll
    for (int nt = 0; nt < 2; ++nt) {
        float l = l_run[nt];
        l += __shfl_xor(l, 16, 64);
        l += __shfl_xor(l, 32, 64);
        const float inv = 1.0f / l;
        const int t = twbase + nt * 16 + llo;
        #pragma unroll
        for (int mc = 0; mc < 4; ++mc)
            #pragma unroll
            for (int r = 0; r < 4; ++r) {
                const int c = mc * 16 + lhi * 4 + r;
                ob[c * 2048 + t] = O[nt][mc][r] * inv;
            }
    }
}

// ---------------------------------------------------- fallback: verbatim V1
__global__ __launch_bounds__(256, 4) void attn_v1(const float* __restrict__ qkv,
                                                  float* __restrict__ out)
{
    __shared__ _Float16 Kt[64 * 64];
    __shared__ _Float16 Vt[64 * 64];
    __shared__ _Float16 Pt[128 * 64];

    const int tid  = threadIdx.x;
    const int wave = tid >> 6;
    const int lane = tid & 63;
    const int llo  = lane & 15;
    const int lhi  = lane >> 4;

    const int blk  = blockIdx.x;
    const int slot = blk >> 3;
    const int bh   = (blk & 7) * 8 + (slot >> 4);
    const int tile = slot & 15;
    const int t0   = tile * 128;

    const float* qb = qkv + (size_t)bh * 393216;
    const float* kb = qb + 131072;
    const float* vb = qb + 262144;

    const float C  = 0.125f * 1.44269504088896f;
    const float B2 = 6.0f;

    half8 qf[2][2];
    const int twbase = t0 + wave * 32;
    #pragma unroll
    for (int nt = 0; nt < 2; ++nt) {
        const int t = twbase + nt * 16 + llo;
        #pragma unroll
        for (int ck = 0; ck < 2; ++ck)
            #pragma unroll
            for (int j = 0; j < 8; ++j) {
                const int c = ck * 32 + lhi * 8 + j;
                qf[nt][ck][j] = (_Float16)(qb[c * 2048 + t] * C);
            }
    }

    const int kc4 = (tid >> 4) * 4;
    const int ksq = (tid & 15) * 4;
    const int vc  = tid >> 4;
    const int vs  = (tid & 15) * 4;

    int kwoff[4];
    #pragma unroll
    for (int sr = 0; sr < 4; ++sr) {
        const int s  = ksq + sr;
        const int sw = ((s >> 2) ^ s) & 7;
        kwoff[sr] = s * 64 + ((((kc4 >> 3) ^ sw) & 7) << 3) + (kc4 & 7);
    }
    int vwoff[4];
    #pragma unroll
    for (int i = 0; i < 4; ++i) {
        const int c = vc + 16 * i;
        vwoff[i] = c * 64 + ((((vs >> 3) ^ (c & 7)) & 7) << 3) + (vs & 7);
    }
    int kroff[4][2];
    #pragma unroll
    for (int ms = 0; ms < 4; ++ms) {
        const int s  = ms * 16 + llo;
        const int sw = ((s >> 2) ^ s) & 7;
        kroff[ms][0] = s * 64 + (((lhi ^ sw) & 7) << 3);
        kroff[ms][1] = s * 64 + ((((lhi + 4) ^ sw) & 7) << 3);
    }
    int pwoff[2][4];
    #pragma unroll
    for (int nt = 0; nt < 2; ++nt) {
        const int row = wave * 32 + nt * 16 + llo;
        #pragma unroll
        for (int ms = 0; ms < 4; ++ms)
            pwoff[nt][ms] = row * 64 + ((((2 * ms + (lhi >> 1)) ^ (llo & 7)) & 7) << 3)
                          + 4 * (lhi & 1);
    }
    int proff[2][2];
    #pragma unroll
    for (int nt = 0; nt < 2; ++nt) {
        const int row = wave * 32 + nt * 16 + llo;
        #pragma unroll
        for (int sk = 0; sk < 2; ++sk)
            proff[nt][sk] = row * 64 + ((((sk * 4 + lhi) ^ (llo & 7)) & 7) << 3);
    }
    int vroff[4][2];
    #pragma unroll
    for (int mc = 0; mc < 4; ++mc) {
        const int row = mc * 16 + llo;
        #pragma unroll
        for (int sk = 0; sk < 2; ++sk)
            vroff[mc][sk] = row * 64 + ((((sk * 4 + lhi) ^ (llo & 7)) & 7) << 3);
    }

    floatx4 kr[4], vr[4];
    auto loadKV = [&](int s0) {
        #pragma unroll
        for (int r = 0; r < 4; ++r)
            kr[r] = *reinterpret_cast<const floatx4*>(kb + (kc4 + r) * 2048 + s0 + ksq);
        #pragma unroll
        for (int i = 0; i < 4; ++i)
            vr[i] = *reinterpret_cast<const floatx4*>(vb + (vc + 16 * i) * 2048 + s0 + vs);
    };
    auto storeKV = [&]() {
        #pragma unroll
        for (int sr = 0; sr < 4; ++sr) {
            half4 h = { (_Float16)kr[0][sr], (_Float16)kr[1][sr],
                        (_Float16)kr[2][sr], (_Float16)kr[3][sr] };
            *reinterpret_cast<half4*>(&Kt[kwoff[sr]]) = h;
        }
        #pragma unroll
        for (int i = 0; i < 4; ++i) {
            half4 h = { (_Float16)vr[i][0], (_Float16)vr[i][1],
                        (_Float16)vr[i][2], (_Float16)vr[i][3] };
            *reinterpret_cast<half4*>(&Vt[vwoff[i]]) = h;
        }
    };

    floatx4 O[2][4];
    #pragma unroll
    for (int nt = 0; nt < 2; ++nt)
        #pragma unroll
        for (int mc = 0; mc < 4; ++mc)
            O[nt][mc] = (floatx4){0.f, 0.f, 0.f, 0.f};
    float l_run[2] = {0.f, 0.f};

    loadKV(0);

    for (int it = 0; it < 32; ++it) {
        __syncthreads();
        storeKV();
        __syncthreads();
        if (it + 1 < 32) loadKV((it + 1) * 64);

        #pragma unroll
        for (int ms = 0; ms < 4; ++ms) {
            half8 a0 = *reinterpret_cast<const half8*>(&Kt[kroff[ms][0]]);
            half8 a1 = *reinterpret_cast<const half8*>(&Kt[kroff[ms][1]]);
            #pragma unroll
            for (int nt = 0; nt < 2; ++nt) {
                floatx4 acc = (floatx4){-B2, -B2, -B2, -B2};
                acc = __builtin_amdgcn_mfma_f32_16x16x32_f16(a0, qf[nt][0], acc, 0, 0, 0);
                acc = __builtin_amdgcn_mfma_f32_16x16x32_f16(a1, qf[nt][1], acc, 0, 0, 0);
                half4 ph;
                float l = 0.f;
                #pragma unroll
                for (int r = 0; r < 4; ++r) {
                    const float p = __builtin_amdgcn_exp2f(acc[r]);
                    l += p;
                    ph[r] = (_Float16)p;
                }
                l_run[nt] += l;
                *reinterpret_cast<half4*>(&Pt[pwoff[nt][ms]]) = ph;
            }
        }

        #pragma unroll
        for (int sk = 0; sk < 2; ++sk) {
            half8 bp[2];
            #pragma unroll
            for (int nt = 0; nt < 2; ++nt)
                bp[nt] = *reinterpret_cast<const half8*>(&Pt[proff[nt][sk]]);
            #pragma unroll
            for (int mc = 0; mc < 4; ++mc) {
                half8 av = *reinterpret_cast<const half8*>(&Vt[vroff[mc][sk]]);
                #pragma unroll
                for (int nt = 0; nt < 2; ++nt)
                    O[nt][mc] = __builtin_amdgcn_mfma_f32_16x16x32_f16(av, bp[nt], O[nt][mc], 0, 0, 0);
            }
        }
    }

    float* ob = out + (size_t)bh * 131072;
    #pragma unroll
    for (int nt = 0; nt < 2; ++nt) {
        float l = l_run[nt];
        l += __shfl_xor(l, 16, 64);
        l += __shfl_xor(l, 32, 64);
        const float inv = 1.0f / l;
        const int t = twbase + nt * 16 + llo;
        #pragma unroll
        for (int mc = 0; mc < 4; ++mc)
            #pragma unroll
            for (int r = 0; r < 4; ++r) {
                const int c = mc * 16 + lhi * 4 + r;
                ob[c * 2048 + t] = O[nt][mc][r] * inv;
            }
    }
}

extern "C" void kernel_launch(void* const* d_in, const int* in_sizes, int n_in,
                              void* d_out, int out_size, void* d_ws, size_t ws_size,
                              hipStream_t stream) {
    const float* qkv = (const float*)d_in[0];
    float* out = (float*)d_out;
    if (d_ws != nullptr && ws_size >= 50331648) {
        _Float16* ws = (_Float16*)d_ws;
        prep_kernel<<<dim3(5120), dim3(256), 0, stream>>>(qkv, ws);
        attn_kernel<<<dim3(1024), dim3(256), 0, stream>>>(ws, out);
    } else {
        attn_v1<<<dim3(1024), dim3(256), 0, stream>>>(qkv, out);
    }
}